// Round 1
// baseline (396.288 us; speedup 1.0000x reference)
//
#include <hip/hip_runtime.h>
#include <hip/hip_bf16.h>
#include <cstdint>

#define NB   2
#define NC   256
#define NSP  32768     // D*H*W
#define NG   32
#define CPG  8         // NC/NG
#define NH   8
#define HDIM 32
#define O3   768
#define GN_EPS 1e-5f

typedef __attribute__((ext_vector_type(4))) float f32x4;
typedef __attribute__((ext_vector_type(8))) short short8;

static __device__ __forceinline__ float bf2f(unsigned short u) {
    union { unsigned int i; float f; } v; v.i = ((unsigned int)u) << 16; return v.f;
}
static __device__ __forceinline__ unsigned short f2bf(float f) {
    union { float f; unsigned int i; } v; v.f = f;
    unsigned int lsb = (v.i >> 16) & 1u;
    return (unsigned short)((v.i + 0x7fffu + lsb) >> 16);
}
static __device__ __forceinline__ float elu1(float x) {
    return x > 0.f ? x + 1.f : __expf(x);
}

// ---------------- weight fp32 -> bf16 ----------------
__global__ __launch_bounds__(256) void k_convw(const float* __restrict__ qkvw,
                                               const float* __restrict__ outw,
                                               unsigned short* __restrict__ w16,
                                               unsigned short* __restrict__ ow16) {
    int i = blockIdx.x * 256 + threadIdx.x;
    for (int idx = i; idx < O3 * NC; idx += gridDim.x * 256) w16[idx] = f2bf(qkvw[idx]);
    for (int idx = i; idx < NC * NC; idx += gridDim.x * 256) ow16[idx] = f2bf(outw[idx]);
}

// ---------------- per-(b,c) sum/sumsq, fp32 input ----------------
__global__ __launch_bounds__(256) void k_stat_f32(const float* __restrict__ x, float* __restrict__ part) {
    int bc = blockIdx.x;
    const float* p = x + (size_t)bc * NSP;
    int t = threadIdx.x;
    float s = 0.f, s2 = 0.f;
    for (int i = t * 4; i < NSP; i += 256 * 4) {
        float4 v = *reinterpret_cast<const float4*>(p + i);
        s  += v.x + v.y + v.z + v.w;
        s2 += v.x * v.x + v.y * v.y + v.z * v.z + v.w * v.w;
    }
    #pragma unroll
    for (int o = 32; o > 0; o >>= 1) { s += __shfl_down(s, o, 64); s2 += __shfl_down(s2, o, 64); }
    __shared__ float red[8];
    if ((t & 63) == 0) { red[(t >> 6) * 2] = s; red[(t >> 6) * 2 + 1] = s2; }
    __syncthreads();
    if (t == 0) {
        part[bc * 2]     = red[0] + red[2] + red[4] + red[6];
        part[bc * 2 + 1] = red[1] + red[3] + red[5] + red[7];
    }
}

// ---------------- per-(b,c) sum/sumsq, bf16 input ----------------
__global__ __launch_bounds__(256) void k_stat_bf16(const unsigned short* __restrict__ y, float* __restrict__ part) {
    int bc = blockIdx.x;
    const unsigned short* p = y + (size_t)bc * NSP;
    int t = threadIdx.x;
    float s = 0.f, s2 = 0.f;
    for (int i = t * 8; i < NSP; i += 256 * 8) {
        short8 v = *reinterpret_cast<const short8*>(p + i);
        #pragma unroll
        for (int j = 0; j < 8; ++j) { float f = bf2f((unsigned short)v[j]); s += f; s2 += f * f; }
    }
    #pragma unroll
    for (int o = 32; o > 0; o >>= 1) { s += __shfl_down(s, o, 64); s2 += __shfl_down(s2, o, 64); }
    __shared__ float red[8];
    if ((t & 63) == 0) { red[(t >> 6) * 2] = s; red[(t >> 6) * 2 + 1] = s2; }
    __syncthreads();
    if (t == 0) {
        part[bc * 2]     = red[0] + red[2] + red[4] + red[6];
        part[bc * 2 + 1] = red[1] + red[3] + red[5] + red[7];
    }
}

// ---------------- finalize group stats: per (b,g) mu, rsig ----------------
__global__ __launch_bounds__(64) void k_gnfin(const float* __restrict__ part, float* __restrict__ stat) {
    int i = threadIdx.x;
    if (i < NB * NG) {
        int b = i / NG, g = i % NG;
        float s = 0.f, s2 = 0.f;
        #pragma unroll
        for (int cc = 0; cc < CPG; ++cc) {
            int bc = b * NC + g * CPG + cc;
            s += part[bc * 2]; s2 += part[bc * 2 + 1];
        }
        float cnt = (float)(CPG * NSP);
        float mu = s / cnt;
        float var = s2 / cnt - mu * mu;
        stat[i * 2] = mu;
        stat[i * 2 + 1] = rsqrtf(var + GN_EPS);
    }
}

// ---------------- fused gn1-apply + qkv GEMM + bias + elu, store q/k/v bf16 ----------------
// grid (NSP/32, NB), 256 threads. MFMA 16x16x32 bf16, output tile 768 x 32 per block.
__global__ __launch_bounds__(256) void k_qkv(const float* __restrict__ x,
                                             const float* __restrict__ nw, const float* __restrict__ nb,
                                             const unsigned short* __restrict__ w16,
                                             const float* __restrict__ qkvb,
                                             const float* __restrict__ gn1,
                                             unsigned short* __restrict__ qb,
                                             unsigned short* __restrict__ kb,
                                             unsigned short* __restrict__ vb) {
    __shared__ unsigned short hbT[32][264];   // h transposed: [n][c], pad 8 -> 528B row stride
    int b = blockIdx.y;
    int n0 = blockIdx.x * 32;
    int t = threadIdx.x;

    // stage h = (x - mu)*rsig*nw + nb  (transposed into LDS, bf16)
    {
        int j = t & 7, cr = t >> 3;                   // 8 f32x4-segs per row, 32 rows/pass
        #pragma unroll
        for (int it = 0; it < 8; ++it) {
            int c = it * 32 + cr;
            float4 v = *reinterpret_cast<const float4*>(x + ((size_t)(b * NC + c)) * NSP + n0 + j * 4);
            int g = c >> 3;
            float mu = gn1[(b * NG + g) * 2], rs = gn1[(b * NG + g) * 2 + 1];
            float sc = rs * nw[c];
            float bi = nb[c] - mu * sc;
            hbT[j * 4 + 0][c] = f2bf(v.x * sc + bi);
            hbT[j * 4 + 1][c] = f2bf(v.y * sc + bi);
            hbT[j * 4 + 2][c] = f2bf(v.z * sc + bi);
            hbT[j * 4 + 3][c] = f2bf(v.w * sc + bi);
        }
    }
    __syncthreads();

    int w = t >> 6, l = t & 63;
    int mr = l & 15, kg = l >> 4;
    for (int mp = 0; mp < 3; ++mp) {
        int rowbase = w * 192 + mp * 64;
        f32x4 acc[4][2];
        #pragma unroll
        for (int a = 0; a < 4; ++a)
            #pragma unroll
            for (int n2 = 0; n2 < 2; ++n2) acc[a][n2] = (f32x4){0.f, 0.f, 0.f, 0.f};
        #pragma unroll
        for (int kc = 0; kc < 8; ++kc) {
            int k0 = kc * 32 + kg * 8;
            short8 af[4], bfr[2];
            #pragma unroll
            for (int mt = 0; mt < 4; ++mt) {
                int arow = rowbase + mt * 16 + mr;
                af[mt] = *reinterpret_cast<const short8*>(w16 + (size_t)arow * NC + k0);
            }
            #pragma unroll
            for (int nt2 = 0; nt2 < 2; ++nt2)
                bfr[nt2] = *reinterpret_cast<const short8*>(&hbT[nt2 * 16 + mr][k0]);
            #pragma unroll
            for (int mt = 0; mt < 4; ++mt)
                #pragma unroll
                for (int nt2 = 0; nt2 < 2; ++nt2)
                    acc[mt][nt2] = __builtin_amdgcn_mfma_f32_16x16x32_bf16(af[mt], bfr[nt2], acc[mt][nt2], 0, 0, 0);
        }
        // epilogue: + bias, elu for q/k, store bf16. rowbase is 64-aligned -> q/k/v branch wave-uniform.
        #pragma unroll
        for (int mt = 0; mt < 4; ++mt) {
            int obase = rowbase + mt * 16 + kg * 4;
            #pragma unroll
            for (int nt2 = 0; nt2 < 2; ++nt2) {
                int n = n0 + nt2 * 16 + mr;
                #pragma unroll
                for (int r = 0; r < 4; ++r) {
                    int o = obase + r;
                    float val = acc[mt][nt2][r] + qkvb[o];
                    if (o < NC) {
                        qb[((size_t)(b * NC + o)) * NSP + n] = f2bf(elu1(val));
                    } else if (o < 2 * NC) {
                        kb[((size_t)(b * NC + (o - NC))) * NSP + n] = f2bf(elu1(val));
                    } else {
                        vb[((size_t)(b * NC + (o - 2 * NC))) * NSP + n] = f2bf(val);
                    }
                }
            }
        }
    }
}

// ---------------- KV = sum_n k_raw * v, S = sum_n k_raw ----------------
// grid (NSP/256, NH, NB), 256 threads
__global__ __launch_bounds__(256) void k_kv(const unsigned short* __restrict__ kb,
                                            const unsigned short* __restrict__ vb,
                                            float* __restrict__ KV, float* __restrict__ S) {
    __shared__ unsigned short kt[32][264];
    __shared__ unsigned short vt[32][264];
    int b = blockIdx.z, h = blockIdx.y;
    int n0 = blockIdx.x * 256;
    int t = threadIdx.x;
    {
        int d8 = t >> 5, seg = t & 31;
        #pragma unroll
        for (int it = 0; it < 4; ++it) {
            int d = it * 8 + d8;
            size_t gofs = ((size_t)(b * NC + h * HDIM + d)) * NSP + n0 + seg * 8;
            *reinterpret_cast<short8*>(&kt[d][seg * 8]) = *reinterpret_cast<const short8*>(kb + gofs);
            *reinterpret_cast<short8*>(&vt[d][seg * 8]) = *reinterpret_cast<const short8*>(vb + gofs);
        }
    }
    __syncthreads();
    int e = t & 31, dg = t >> 5;          // d = dg*4 + i
    float acc4[4] = {0.f, 0.f, 0.f, 0.f};
    #pragma unroll 8
    for (int n = 0; n < 256; ++n) {
        float vv = bf2f(vt[e][n]);
        #pragma unroll
        for (int i = 0; i < 4; ++i) acc4[i] += bf2f(kt[dg * 4 + i][n]) * vv;
    }
    #pragma unroll
    for (int i = 0; i < 4; ++i)
        atomicAdd(&KV[(((b * NH) + h) * HDIM + dg * 4 + i) * HDIM + e], acc4[i]);
    if (t < 32) {
        float s = 0.f;
        #pragma unroll 8
        for (int n = 0; n < 256; ++n) s += bf2f(kt[t][n]);
        atomicAdd(&S[(b * NH + h) * HDIM + t], s);
    }
}

// ---------------- KV2 = KV / max(S,1e-6) ----------------
__global__ __launch_bounds__(256) void k_kvfin(const float* __restrict__ KV, const float* __restrict__ S,
                                               float* __restrict__ KV2) {
    int i = blockIdx.x * 256 + threadIdx.x;
    if (i < NB * NH * HDIM * HDIM) {
        int de = i & (HDIM * HDIM - 1);
        int bh = i / (HDIM * HDIM);
        int d = de >> 5;
        KV2[i] = KV[i] / fmaxf(S[bh * HDIM + d], 1e-6f);
    }
}

// ---------------- fused attn (q*KV2 / qsum) + out GEMM + bias, store y bf16 ----------------
// grid (NSP/32, NB), 256 threads
__global__ __launch_bounds__(256) void k_attn(const unsigned short* __restrict__ qb,
                                              const float* __restrict__ KV2,
                                              const unsigned short* __restrict__ ow16,
                                              const float* __restrict__ outb,
                                              unsigned short* __restrict__ yb) {
    __shared__ unsigned short qT[32][264];   // q transposed [n][c]
    __shared__ unsigned short aT[32][264];   // attn transposed [n][c]
    __shared__ float qs[NH][32];
    int b = blockIdx.y, n0 = blockIdx.x * 32, t = threadIdx.x;

    {   // stage q transposed
        int seg = t & 3, cr = t >> 2;
        #pragma unroll
        for (int it = 0; it < 4; ++it) {
            int c = it * 64 + cr;
            short8 v = *reinterpret_cast<const short8*>(qb + ((size_t)(b * NC + c)) * NSP + n0 + seg * 8);
            #pragma unroll
            for (int q2 = 0; q2 < 8; ++q2) qT[seg * 8 + q2][c] = (unsigned short)v[q2];
        }
    }
    __syncthreads();
    {   // qsum per (h, n)
        int h = t >> 5, n = t & 31;
        float s = 0.f;
        #pragma unroll
        for (int ch = 0; ch < 4; ++ch) {
            short8 v = *reinterpret_cast<const short8*>(&qT[n][h * HDIM + ch * 8]);
            #pragma unroll
            for (int j = 0; j < 8; ++j) s += bf2f((unsigned short)v[j]);
        }
        qs[h][n] = fmaxf(s, 1e-6f);
    }
    __syncthreads();
    {   // attn[c][n] = (sum_d KV2[d][e] * q[h*32+d][n]) / qs
        int c = t, h = c >> 5;
        int e = c & 31;
        float r[32];
        #pragma unroll
        for (int d = 0; d < 32; ++d) r[d] = KV2[((b * NH + h) * HDIM + d) * HDIM + e];
        for (int n = 0; n < 32; ++n) {
            float a = 0.f;
            #pragma unroll
            for (int ch = 0; ch < 4; ++ch) {
                short8 v = *reinterpret_cast<const short8*>(&qT[n][h * HDIM + ch * 8]);
                #pragma unroll
                for (int j = 0; j < 8; ++j) a += r[ch * 8 + j] * bf2f((unsigned short)v[j]);
            }
            aT[n][c] = f2bf(a / qs[h][n]);
        }
    }
    __syncthreads();
    // out GEMM: y[o][n] = sum_c ow[o][c] * attn[c][n] + outb[o]
    int w = t >> 6, l = t & 63, mr = l & 15, kg = l >> 4;
    int rowbase = w * 64;
    f32x4 acc[4][2];
    #pragma unroll
    for (int a = 0; a < 4; ++a)
        #pragma unroll
        for (int n2 = 0; n2 < 2; ++n2) acc[a][n2] = (f32x4){0.f, 0.f, 0.f, 0.f};
    #pragma unroll
    for (int kc = 0; kc < 8; ++kc) {
        int k0 = kc * 32 + kg * 8;
        short8 af[4], bfr[2];
        #pragma unroll
        for (int mt = 0; mt < 4; ++mt)
            af[mt] = *reinterpret_cast<const short8*>(ow16 + (size_t)(rowbase + mt * 16 + mr) * NC + k0);
        #pragma unroll
        for (int nt2 = 0; nt2 < 2; ++nt2)
            bfr[nt2] = *reinterpret_cast<const short8*>(&aT[nt2 * 16 + mr][k0]);
        #pragma unroll
        for (int mt = 0; mt < 4; ++mt)
            #pragma unroll
            for (int nt2 = 0; nt2 < 2; ++nt2)
                acc[mt][nt2] = __builtin_amdgcn_mfma_f32_16x16x32_bf16(af[mt], bfr[nt2], acc[mt][nt2], 0, 0, 0);
    }
    #pragma unroll
    for (int mt = 0; mt < 4; ++mt) {
        int obase = rowbase + mt * 16 + kg * 4;
        #pragma unroll
        for (int nt2 = 0; nt2 < 2; ++nt2) {
            int n = n0 + nt2 * 16 + mr;
            #pragma unroll
            for (int r = 0; r < 4; ++r) {
                int o = obase + r;
                yb[((size_t)(b * NC + o)) * NSP + n] = f2bf(acc[mt][nt2][r] + outb[o]);
            }
        }
    }
}

// ---------------- final: out = x + gn2(y) ----------------
__global__ __launch_bounds__(256) void k_final(const float* __restrict__ x,
                                               const unsigned short* __restrict__ yb,
                                               const float* __restrict__ onw, const float* __restrict__ onb,
                                               const float* __restrict__ gn2, float* __restrict__ out) {
    size_t base = ((size_t)blockIdx.x * 256 + threadIdx.x) * 8;
    int bc = (int)(base >> 15);           // b*NC + c
    int c = bc & (NC - 1);
    int b = bc >> 8;
    int g = c >> 3;
    float mu = gn2[(b * NG + g) * 2], rs = gn2[(b * NG + g) * 2 + 1];
    float sc = rs * onw[c], bi = onb[c] - mu * sc;
    short8 v = *reinterpret_cast<const short8*>(yb + base);
    float4 x0 = *reinterpret_cast<const float4*>(x + base);
    float4 x1 = *reinterpret_cast<const float4*>(x + base + 4);
    float4 o0, o1;
    o0.x = x0.x + bf2f((unsigned short)v[0]) * sc + bi;
    o0.y = x0.y + bf2f((unsigned short)v[1]) * sc + bi;
    o0.z = x0.z + bf2f((unsigned short)v[2]) * sc + bi;
    o0.w = x0.w + bf2f((unsigned short)v[3]) * sc + bi;
    o1.x = x1.x + bf2f((unsigned short)v[4]) * sc + bi;
    o1.y = x1.y + bf2f((unsigned short)v[5]) * sc + bi;
    o1.z = x1.z + bf2f((unsigned short)v[6]) * sc + bi;
    o1.w = x1.w + bf2f((unsigned short)v[7]) * sc + bi;
    *reinterpret_cast<float4*>(out + base) = o0;
    *reinterpret_cast<float4*>(out + base + 4) = o1;
}

extern "C" void kernel_launch(void* const* d_in, const int* in_sizes, int n_in,
                              void* d_out, int out_size, void* d_ws, size_t ws_size,
                              hipStream_t stream) {
    const float* x      = (const float*)d_in[0];
    const float* norm_w = (const float*)d_in[1];
    const float* norm_b = (const float*)d_in[2];
    const float* qkv_w  = (const float*)d_in[3];
    const float* qkv_b  = (const float*)d_in[4];
    const float* out_w  = (const float*)d_in[5];
    const float* out_b  = (const float*)d_in[6];
    const float* onw    = (const float*)d_in[7];
    const float* onb    = (const float*)d_in[8];
    float* out = (float*)d_out;

    char* w = (char*)d_ws;
    size_t off = 0;
    auto al = [&](size_t n) { size_t o = off; off += (n + 255) & ~(size_t)255; return o; };
    const size_t bufsz = (size_t)NB * NC * NSP * 2;          // 33.5 MB each
    unsigned short* qbuf = (unsigned short*)(w + al(bufsz));
    unsigned short* kbuf = (unsigned short*)(w + al(bufsz));
    unsigned short* vbuf = (unsigned short*)(w + al(bufsz));
    unsigned short* ybuf = (unsigned short*)(w + al(bufsz));
    unsigned short* w16  = (unsigned short*)(w + al((size_t)O3 * NC * 2));
    unsigned short* ow16 = (unsigned short*)(w + al((size_t)NC * NC * 2));
    float* gn1part = (float*)(w + al((size_t)NB * NC * 2 * 4));
    float* gn1stat = (float*)(w + al((size_t)NB * NG * 2 * 4));
    float* gn2part = (float*)(w + al((size_t)NB * NC * 2 * 4));
    float* gn2stat = (float*)(w + al((size_t)NB * NG * 2 * 4));
    float* KV  = (float*)(w + al((size_t)NB * NH * HDIM * HDIM * 4));   // followed by S (contiguous)
    float* S   = (float*)(w + al((size_t)NB * NH * HDIM * 4));
    float* KV2 = (float*)(w + al((size_t)NB * NH * HDIM * HDIM * 4));

    hipMemsetAsync(KV, 0, (size_t)NB * NH * HDIM * HDIM * 4 + 256 /*covers S (2048<..pad)*/ + (size_t)NB * NH * HDIM * 4, stream);
    hipMemsetAsync(S, 0, (size_t)NB * NH * HDIM * 4, stream);

    k_convw<<<dim3(256), dim3(256), 0, stream>>>(qkv_w, out_w, w16, ow16);
    k_stat_f32<<<dim3(NB * NC), dim3(256), 0, stream>>>(x, gn1part);
    k_gnfin<<<dim3(1), dim3(64), 0, stream>>>(gn1part, gn1stat);
    k_qkv<<<dim3(NSP / 32, NB), dim3(256), 0, stream>>>(x, norm_w, norm_b, w16, qkv_b, gn1stat,
                                                        qbuf, kbuf, vbuf);
    k_kv<<<dim3(NSP / 256, NH, NB), dim3(256), 0, stream>>>(kbuf, vbuf, KV, S);
    k_kvfin<<<dim3(64), dim3(256), 0, stream>>>(KV, S, KV2);
    k_attn<<<dim3(NSP / 32, NB), dim3(256), 0, stream>>>(qbuf, KV2, ow16, out_b, ybuf);
    k_stat_bf16<<<dim3(NB * NC), dim3(256), 0, stream>>>(ybuf, gn2part);
    k_gnfin<<<dim3(1), dim3(64), 0, stream>>>(gn2part, gn2stat);
    k_final<<<dim3((NB * NC * NSP) / (256 * 8)), dim3(256), 0, stream>>>(x, ybuf, onw, onb, gn2stat, out);
}

// Round 2
// 340.977 us; speedup vs baseline: 1.1622x; 1.1622x over previous
//
#include <hip/hip_runtime.h>
#include <hip/hip_bf16.h>
#include <cstdint>

#define NB   2
#define NC   256
#define NSP  32768     // D*H*W
#define NG   32
#define CPG  8         // NC/NG
#define NH   8
#define HDIM 32
#define O3   768
#define NCH  64        // k_kv spatial chunks
#define GN_EPS 1e-5f

typedef __attribute__((ext_vector_type(4))) float f32x4;
typedef __attribute__((ext_vector_type(8))) short short8;

static __device__ __forceinline__ float bf2f(unsigned short u) {
    union { unsigned int i; float f; } v; v.i = ((unsigned int)u) << 16; return v.f;
}
static __device__ __forceinline__ unsigned short f2bf(float f) {
    union { float f; unsigned int i; } v; v.f = f;
    unsigned int lsb = (v.i >> 16) & 1u;
    return (unsigned short)((v.i + 0x7fffu + lsb) >> 16);
}
static __device__ __forceinline__ float elu1(float x) {
    return x > 0.f ? x + 1.f : __expf(x);
}

// ---------------- weight fp32 -> bf16 ----------------
__global__ __launch_bounds__(256) void k_convw(const float* __restrict__ qkvw,
                                               const float* __restrict__ outw,
                                               unsigned short* __restrict__ w16,
                                               unsigned short* __restrict__ ow16) {
    int i = blockIdx.x * 256 + threadIdx.x;
    for (int idx = i; idx < O3 * NC; idx += gridDim.x * 256) w16[idx] = f2bf(qkvw[idx]);
    for (int idx = i; idx < NC * NC; idx += gridDim.x * 256) ow16[idx] = f2bf(outw[idx]);
}

// ---------------- per-(b,c) sum/sumsq, fp32 input ----------------
__global__ __launch_bounds__(256) void k_stat_f32(const float* __restrict__ x, float* __restrict__ part) {
    int bc = blockIdx.x;
    const float* p = x + (size_t)bc * NSP;
    int t = threadIdx.x;
    float s = 0.f, s2 = 0.f;
    for (int i = t * 4; i < NSP; i += 256 * 4) {
        float4 v = *reinterpret_cast<const float4*>(p + i);
        s  += v.x + v.y + v.z + v.w;
        s2 += v.x * v.x + v.y * v.y + v.z * v.z + v.w * v.w;
    }
    #pragma unroll
    for (int o = 32; o > 0; o >>= 1) { s += __shfl_down(s, o, 64); s2 += __shfl_down(s2, o, 64); }
    __shared__ float red[8];
    if ((t & 63) == 0) { red[(t >> 6) * 2] = s; red[(t >> 6) * 2 + 1] = s2; }
    __syncthreads();
    if (t == 0) {
        part[bc * 2]     = red[0] + red[2] + red[4] + red[6];
        part[bc * 2 + 1] = red[1] + red[3] + red[5] + red[7];
    }
}

// ---------------- per-(b,c) sum/sumsq, bf16 input ----------------
__global__ __launch_bounds__(256) void k_stat_bf16(const unsigned short* __restrict__ y, float* __restrict__ part) {
    int bc = blockIdx.x;
    const unsigned short* p = y + (size_t)bc * NSP;
    int t = threadIdx.x;
    float s = 0.f, s2 = 0.f;
    for (int i = t * 8; i < NSP; i += 256 * 8) {
        short8 v = *reinterpret_cast<const short8*>(p + i);
        #pragma unroll
        for (int j = 0; j < 8; ++j) { float f = bf2f((unsigned short)v[j]); s += f; s2 += f * f; }
    }
    #pragma unroll
    for (int o = 32; o > 0; o >>= 1) { s += __shfl_down(s, o, 64); s2 += __shfl_down(s2, o, 64); }
    __shared__ float red[8];
    if ((t & 63) == 0) { red[(t >> 6) * 2] = s; red[(t >> 6) * 2 + 1] = s2; }
    __syncthreads();
    if (t == 0) {
        part[bc * 2]     = red[0] + red[2] + red[4] + red[6];
        part[bc * 2 + 1] = red[1] + red[3] + red[5] + red[7];
    }
}

// ---------------- finalize group stats: per (b,g) mu, rsig ----------------
__global__ __launch_bounds__(64) void k_gnfin(const float* __restrict__ part, float* __restrict__ stat) {
    int i = threadIdx.x;
    if (i < NB * NG) {
        int b = i / NG, g = i % NG;
        float s = 0.f, s2 = 0.f;
        #pragma unroll
        for (int cc = 0; cc < CPG; ++cc) {
            int bc = b * NC + g * CPG + cc;
            s += part[bc * 2]; s2 += part[bc * 2 + 1];
        }
        float cnt = (float)(CPG * NSP);
        float mu = s / cnt;
        float var = s2 / cnt - mu * mu;
        stat[i * 2] = mu;
        stat[i * 2 + 1] = rsqrtf(var + GN_EPS);
    }
}

// ---------------- fused gn1-apply + qkv GEMM + bias + elu, store q/k/v bf16 ----------------
// grid (NSP/64, NB), 256 threads (4 waves). Block tile 256(M)x64(N), 3 M-passes.
__global__ __launch_bounds__(256) void k_qkv(const float* __restrict__ x,
                                             const float* __restrict__ nw, const float* __restrict__ nb,
                                             const unsigned short* __restrict__ w16,
                                             const float* __restrict__ qkvb,
                                             const float* __restrict__ gn1,
                                             unsigned short* __restrict__ qb,
                                             unsigned short* __restrict__ kb,
                                             unsigned short* __restrict__ vb) {
    __shared__ unsigned short Ht[64][264];   // h transposed: [n][c]
    int b = blockIdx.y;
    int n0 = blockIdx.x * 64;
    int t = threadIdx.x;

    {   // stage h = (x - mu)*rsig*nw + nb, transposed, bf16
        int j = t & 15, cr = t >> 4;
        #pragma unroll
        for (int it = 0; it < 16; ++it) {
            int c = it * 16 + cr;
            float4 v = *reinterpret_cast<const float4*>(x + ((size_t)(b * NC + c)) * NSP + n0 + j * 4);
            int g = c >> 3;
            float mu = gn1[(b * NG + g) * 2], rs = gn1[(b * NG + g) * 2 + 1];
            float sc = rs * nw[c];
            float bi = nb[c] - mu * sc;
            Ht[j * 4 + 0][c] = f2bf(v.x * sc + bi);
            Ht[j * 4 + 1][c] = f2bf(v.y * sc + bi);
            Ht[j * 4 + 2][c] = f2bf(v.z * sc + bi);
            Ht[j * 4 + 3][c] = f2bf(v.w * sc + bi);
        }
    }
    __syncthreads();

    int w = t >> 6, l = t & 63, mr = l & 15, kg = l >> 4;
    for (int mp = 0; mp < 3; ++mp) {
        f32x4 acc[4][4];
        #pragma unroll
        for (int a = 0; a < 4; ++a)
            #pragma unroll
            for (int n2 = 0; n2 < 4; ++n2) acc[a][n2] = (f32x4){0.f, 0.f, 0.f, 0.f};
        #pragma unroll
        for (int kc = 0; kc < 8; ++kc) {
            int k0 = kc * 32 + kg * 8;
            short8 af[4], bfr[4];
            #pragma unroll
            for (int mt = 0; mt < 4; ++mt)
                af[mt] = *reinterpret_cast<const short8*>(w16 + (size_t)(mp * 256 + w * 64 + mt * 16 + mr) * NC + k0);
            #pragma unroll
            for (int nt = 0; nt < 4; ++nt)
                bfr[nt] = *reinterpret_cast<const short8*>(&Ht[nt * 16 + mr][k0]);
            #pragma unroll
            for (int mt = 0; mt < 4; ++mt)
                #pragma unroll
                for (int nt = 0; nt < 4; ++nt)
                    acc[mt][nt] = __builtin_amdgcn_mfma_f32_16x16x32_bf16(af[mt], bfr[nt], acc[mt][nt], 0, 0, 0);
        }
        unsigned short* dst = (mp == 0) ? qb : (mp == 1) ? kb : vb;
        #pragma unroll
        for (int mt = 0; mt < 4; ++mt) {
            #pragma unroll
            for (int nt = 0; nt < 4; ++nt) {
                int n = n0 + nt * 16 + mr;
                #pragma unroll
                for (int r = 0; r < 4; ++r) {
                    int olocal = w * 64 + mt * 16 + kg * 4 + r;
                    float val = acc[mt][nt][r] + qkvb[mp * 256 + olocal];
                    if (mp < 2) val = elu1(val);
                    dst[((size_t)(b * NC + olocal)) * NSP + n] = f2bf(val);
                }
            }
        }
    }
}

// ---------------- KV partials via MFMA: KV[d][e] = sum_n k[d][n] v[e][n] ----------------
// grid (NCH, NH, NB), 256 threads (4 waves). Per block: 512 n, per wave 128 n.
__global__ __launch_bounds__(256) void k_kv(const unsigned short* __restrict__ kb,
                                            const unsigned short* __restrict__ vb,
                                            float* __restrict__ KVpart, float* __restrict__ Spart) {
    int ch = blockIdx.x, h = blockIdx.y, b = blockIdx.z;
    int t = threadIdx.x, w = t >> 6, l = t & 63;
    int d16 = l & 15, kg = l >> 4;
    size_t base = ((size_t)(b * NC + h * HDIM)) * NSP + ch * 512 + w * 128;
    const unsigned short* kp = kb + base;
    const unsigned short* vp = vb + base;

    f32x4 acc[2][2];
    #pragma unroll
    for (int a = 0; a < 2; ++a)
        #pragma unroll
        for (int c = 0; c < 2; ++c) acc[a][c] = (f32x4){0.f, 0.f, 0.f, 0.f};
    float s0 = 0.f, s1 = 0.f;
    #pragma unroll
    for (int step = 0; step < 4; ++step) {
        int nof = step * 32 + kg * 8;
        short8 ak0 = *reinterpret_cast<const short8*>(kp + (size_t)(d16) * NSP + nof);
        short8 ak1 = *reinterpret_cast<const short8*>(kp + (size_t)(16 + d16) * NSP + nof);
        short8 av0 = *reinterpret_cast<const short8*>(vp + (size_t)(d16) * NSP + nof);
        short8 av1 = *reinterpret_cast<const short8*>(vp + (size_t)(16 + d16) * NSP + nof);
        acc[0][0] = __builtin_amdgcn_mfma_f32_16x16x32_bf16(ak0, av0, acc[0][0], 0, 0, 0);
        acc[0][1] = __builtin_amdgcn_mfma_f32_16x16x32_bf16(ak0, av1, acc[0][1], 0, 0, 0);
        acc[1][0] = __builtin_amdgcn_mfma_f32_16x16x32_bf16(ak1, av0, acc[1][0], 0, 0, 0);
        acc[1][1] = __builtin_amdgcn_mfma_f32_16x16x32_bf16(ak1, av1, acc[1][1], 0, 0, 0);
        #pragma unroll
        for (int j = 0; j < 8; ++j) { s0 += bf2f((unsigned short)ak0[j]); s1 += bf2f((unsigned short)ak1[j]); }
    }
    // reduce S over the 4 lanes sharing d16 (kg 0..3)
    s0 += __shfl_down(s0, 32, 64); s0 += __shfl_down(s0, 16, 64);
    s1 += __shfl_down(s1, 32, 64); s1 += __shfl_down(s1, 16, 64);

    __shared__ float red[4][1024];
    __shared__ float sred[4][32];
    #pragma unroll
    for (int et = 0; et < 2; ++et)
        #pragma unroll
        for (int nt = 0; nt < 2; ++nt)
            #pragma unroll
            for (int r = 0; r < 4; ++r) {
                int d = et * 16 + kg * 4 + r;
                int e = nt * 16 + d16;
                red[w][d * 32 + e] = acc[et][nt][r];
            }
    if (l < 16) { sred[w][l] = s0; sred[w][16 + l] = s1; }
    __syncthreads();
    int bh = b * NH + h;
    float* kvout = KVpart + ((size_t)bh * NCH + ch) * 1024;
    for (int i = t; i < 1024; i += 256) kvout[i] = red[0][i] + red[1][i] + red[2][i] + red[3][i];
    if (t < 32) Spart[(bh * NCH + ch) * 32 + t] = sred[0][t] + sred[1][t] + sred[2][t] + sred[3][t];
}

// ---------------- reduce partials, KV2bf[e][d] = bf16(KV[d][e]/max(S[d],1e-6)) ----------------
__global__ __launch_bounds__(256) void k_kvfin(const float* __restrict__ KVpart, const float* __restrict__ Spart,
                                               unsigned short* __restrict__ KV2bf) {
    int bh = blockIdx.x, t = threadIdx.x;
    __shared__ float Sl[32];
    __shared__ float kvred[1024];
    if (t < 32) {
        float s = 0.f;
        for (int ch = 0; ch < NCH; ++ch) s += Spart[(bh * NCH + ch) * 32 + t];
        Sl[t] = fmaxf(s, 1e-6f);
    }
    for (int i = t; i < 1024; i += 256) {
        float s = 0.f;
        #pragma unroll 8
        for (int ch = 0; ch < NCH; ++ch) s += KVpart[((size_t)bh * NCH + ch) * 1024 + i];
        kvred[i] = s;
    }
    __syncthreads();
    for (int i = t; i < 1024; i += 256) {
        int d = i >> 5, e = i & 31;
        KV2bf[bh * 1024 + e * 32 + d] = f2bf(kvred[d * 32 + e] / Sl[d]);
    }
}

// ---------------- fused attn (MFMA) + out GEMM + bias, store y bf16 ----------------
// grid (NSP/128, NB), 512 threads (8 waves). attn: wave = head. out-GEMM: 256x128 tile.
__global__ __launch_bounds__(512) void k_attn(const unsigned short* __restrict__ qb,
                                              const unsigned short* __restrict__ KV2bf,
                                              const unsigned short* __restrict__ ow16,
                                              const float* __restrict__ outb,
                                              unsigned short* __restrict__ yb) {
    __shared__ unsigned short qT[128][264];   // q transposed [n][c]; reused in-place as attn [n][c]
    __shared__ float qsr[NH][128];
    int b = blockIdx.y, n0 = blockIdx.x * 128, t = threadIdx.x;

    {   // stage q transposed
        int j = t & 15, cr = t >> 4;
        #pragma unroll
        for (int it = 0; it < 8; ++it) {
            int c = it * 32 + cr;
            short8 v = *reinterpret_cast<const short8*>(qb + ((size_t)(b * NC + c)) * NSP + n0 + j * 8);
            #pragma unroll
            for (int q2 = 0; q2 < 8; ++q2) qT[j * 8 + q2][c] = (unsigned short)v[q2];
        }
    }
    __syncthreads();
    int wid = t >> 6, l = t & 63;
    int h = wid;                       // wave = head
    int mr = l & 15, kg = l >> 4;
    {   // qsum per (h, n)
        for (int nn = l; nn < 128; nn += 64) {
            float s = 0.f;
            #pragma unroll
            for (int chh = 0; chh < 4; ++chh) {
                short8 v = *reinterpret_cast<const short8*>(&qT[nn][h * HDIM + chh * 8]);
                #pragma unroll
                for (int j = 0; j < 8; ++j) s += bf2f((unsigned short)v[j]);
            }
            qsr[h][nn] = fmaxf(s, 1e-6f);
        }
    }
    __syncthreads();
    {   // attn: per head, D[e][n] = sum_d KV2[d][e] q[d][n]; in-place into qT columns h*32..
        short8 a0 = *reinterpret_cast<const short8*>(KV2bf + (b * NH + h) * 1024 + (0 * 16 + mr) * 32 + kg * 8);
        short8 a1 = *reinterpret_cast<const short8*>(KV2bf + (b * NH + h) * 1024 + (1 * 16 + mr) * 32 + kg * 8);
        #pragma unroll
        for (int half = 0; half < 2; ++half) {
            short8 bfr[4];
            f32x4 acc[2][4];
            #pragma unroll
            for (int nt = 0; nt < 4; ++nt) {
                bfr[nt] = *reinterpret_cast<const short8*>(&qT[half * 64 + nt * 16 + mr][h * HDIM + kg * 8]);
                acc[0][nt] = (f32x4){0.f, 0.f, 0.f, 0.f};
                acc[1][nt] = (f32x4){0.f, 0.f, 0.f, 0.f};
            }
            #pragma unroll
            for (int nt = 0; nt < 4; ++nt) {
                acc[0][nt] = __builtin_amdgcn_mfma_f32_16x16x32_bf16(a0, bfr[nt], acc[0][nt], 0, 0, 0);
                acc[1][nt] = __builtin_amdgcn_mfma_f32_16x16x32_bf16(a1, bfr[nt], acc[1][nt], 0, 0, 0);
            }
            #pragma unroll
            for (int et = 0; et < 2; ++et)
                #pragma unroll
                for (int nt = 0; nt < 4; ++nt) {
                    int n = half * 64 + nt * 16 + mr;
                    float inv = 1.0f / qsr[h][n];
                    #pragma unroll
                    for (int r = 0; r < 4; ++r) {
                        int c = h * HDIM + et * 16 + kg * 4 + r;
                        qT[n][c] = f2bf(acc[et][nt][r] * inv);
                    }
                }
        }
    }
    __syncthreads();
    // out GEMM: y[o][n] = sum_c ow[o][c] * attn[c][n] + outb[o]
    int wr = wid >> 1, wc = wid & 1;
    f32x4 acc[4][4];
    #pragma unroll
    for (int a = 0; a < 4; ++a)
        #pragma unroll
        for (int n2 = 0; n2 < 4; ++n2) acc[a][n2] = (f32x4){0.f, 0.f, 0.f, 0.f};
    #pragma unroll
    for (int kc = 0; kc < 8; ++kc) {
        int k0 = kc * 32 + kg * 8;
        short8 af[4], bfr[4];
        #pragma unroll
        for (int mt = 0; mt < 4; ++mt)
            af[mt] = *reinterpret_cast<const short8*>(ow16 + (size_t)(wr * 64 + mt * 16 + mr) * NC + k0);
        #pragma unroll
        for (int nt = 0; nt < 4; ++nt)
            bfr[nt] = *reinterpret_cast<const short8*>(&qT[wc * 64 + nt * 16 + mr][k0]);
        #pragma unroll
        for (int mt = 0; mt < 4; ++mt)
            #pragma unroll
            for (int nt = 0; nt < 4; ++nt)
                acc[mt][nt] = __builtin_amdgcn_mfma_f32_16x16x32_bf16(af[mt], bfr[nt], acc[mt][nt], 0, 0, 0);
    }
    #pragma unroll
    for (int mt = 0; mt < 4; ++mt) {
        #pragma unroll
        for (int nt = 0; nt < 4; ++nt) {
            int n = n0 + wc * 64 + nt * 16 + mr;
            #pragma unroll
            for (int r = 0; r < 4; ++r) {
                int o = wr * 64 + mt * 16 + kg * 4 + r;
                yb[((size_t)(b * NC + o)) * NSP + n] = f2bf(acc[mt][nt][r] + outb[o]);
            }
        }
    }
}

// ---------------- final: out = x + gn2(y) ----------------
__global__ __launch_bounds__(256) void k_final(const float* __restrict__ x,
                                               const unsigned short* __restrict__ yb,
                                               const float* __restrict__ onw, const float* __restrict__ onb,
                                               const float* __restrict__ gn2, float* __restrict__ out) {
    size_t base = ((size_t)blockIdx.x * 256 + threadIdx.x) * 8;
    int bc = (int)(base >> 15);           // b*NC + c
    int c = bc & (NC - 1);
    int b = bc >> 8;
    int g = c >> 3;
    float mu = gn2[(b * NG + g) * 2], rs = gn2[(b * NG + g) * 2 + 1];
    float sc = rs * onw[c], bi = onb[c] - mu * sc;
    short8 v = *reinterpret_cast<const short8*>(yb + base);
    float4 x0 = *reinterpret_cast<const float4*>(x + base);
    float4 x1 = *reinterpret_cast<const float4*>(x + base + 4);
    float4 o0, o1;
    o0.x = x0.x + bf2f((unsigned short)v[0]) * sc + bi;
    o0.y = x0.y + bf2f((unsigned short)v[1]) * sc + bi;
    o0.z = x0.z + bf2f((unsigned short)v[2]) * sc + bi;
    o0.w = x0.w + bf2f((unsigned short)v[3]) * sc + bi;
    o1.x = x1.x + bf2f((unsigned short)v[4]) * sc + bi;
    o1.y = x1.y + bf2f((unsigned short)v[5]) * sc + bi;
    o1.z = x1.z + bf2f((unsigned short)v[6]) * sc + bi;
    o1.w = x1.w + bf2f((unsigned short)v[7]) * sc + bi;
    *reinterpret_cast<float4*>(out + base) = o0;
    *reinterpret_cast<float4*>(out + base + 4) = o1;
}

extern "C" void kernel_launch(void* const* d_in, const int* in_sizes, int n_in,
                              void* d_out, int out_size, void* d_ws, size_t ws_size,
                              hipStream_t stream) {
    const float* x      = (const float*)d_in[0];
    const float* norm_w = (const float*)d_in[1];
    const float* norm_b = (const float*)d_in[2];
    const float* qkv_w  = (const float*)d_in[3];
    const float* qkv_b  = (const float*)d_in[4];
    const float* out_w  = (const float*)d_in[5];
    const float* out_b  = (const float*)d_in[6];
    const float* onw    = (const float*)d_in[7];
    const float* onb    = (const float*)d_in[8];
    float* out = (float*)d_out;

    char* w = (char*)d_ws;
    size_t off = 0;
    auto al = [&](size_t n) { size_t o = off; off += (n + 255) & ~(size_t)255; return o; };
    const size_t bufsz = (size_t)NB * NC * NSP * 2;          // 33.5 MB each
    unsigned short* qbuf = (unsigned short*)(w + al(bufsz));
    unsigned short* kbuf = (unsigned short*)(w + al(bufsz));
    unsigned short* vbuf = (unsigned short*)(w + al(bufsz));
    unsigned short* ybuf = (unsigned short*)(w + al(bufsz));
    unsigned short* w16  = (unsigned short*)(w + al((size_t)O3 * NC * 2));
    unsigned short* ow16 = (unsigned short*)(w + al((size_t)NC * NC * 2));
    float* gn1part = (float*)(w + al((size_t)NB * NC * 2 * 4));
    float* gn1stat = (float*)(w + al((size_t)NB * NG * 2 * 4));
    float* gn2part = (float*)(w + al((size_t)NB * NC * 2 * 4));
    float* gn2stat = (float*)(w + al((size_t)NB * NG * 2 * 4));
    unsigned short* KV2bf = (unsigned short*)(w + al((size_t)NB * NH * HDIM * HDIM * 2));
    // KVpart/Spart alias ybuf: fully consumed by k_kvfin before k_attn writes ybuf.
    float* KVpart = (float*)ybuf;                                        // 16*NCH*1024*4 = 4 MB
    float* Spart  = (float*)(ybuf + (size_t)NB * NH * NCH * 1024 * 2);   // after KVpart (elem offset in shorts)

    k_convw<<<dim3(256), dim3(256), 0, stream>>>(qkv_w, out_w, w16, ow16);
    k_stat_f32<<<dim3(NB * NC), dim3(256), 0, stream>>>(x, gn1part);
    k_gnfin<<<dim3(1), dim3(64), 0, stream>>>(gn1part, gn1stat);
    k_qkv<<<dim3(NSP / 64, NB), dim3(256), 0, stream>>>(x, norm_w, norm_b, w16, qkv_b, gn1stat,
                                                        qbuf, kbuf, vbuf);
    k_kv<<<dim3(NCH, NH, NB), dim3(256), 0, stream>>>(kbuf, vbuf, KVpart, Spart);
    k_kvfin<<<dim3(NB * NH), dim3(256), 0, stream>>>(KVpart, Spart, KV2bf);
    k_attn<<<dim3(NSP / 128, NB), dim3(512), 0, stream>>>(qbuf, KV2bf, ow16, out_b, ybuf);
    k_stat_bf16<<<dim3(NB * NC), dim3(256), 0, stream>>>(ybuf, gn2part);
    k_gnfin<<<dim3(1), dim3(64), 0, stream>>>(gn2part, gn2stat);
    k_final<<<dim3((NB * NC * NSP) / (256 * 8)), dim3(256), 0, stream>>>(x, ybuf, onw, onb, gn2stat, out);
}